// Round 5
// baseline (263.866 us; speedup 1.0000x reference)
//
#include <hip/hip_runtime.h>

// PoolingAggregator: out[b,g] = mean over {t : segment_ids[t]==g} of feat[b, flat_indices[t]]
// B=512, N=10000, G=2048, T=131072.
//
// SINGLE persistent kernel, grid = 1024 blocks x 256 thr, __launch_bounds__(256,4)
// -> exactly 4 blocks/CU co-resident (LDS 20.6KB < 40KB budget) so the hand-rolled
// device-scope grid barrier cannot deadlock. Barrier counter lives in d_ws and is
// zeroed each call with hipMemsetAsync (graph-capture legal).
//
// Phase A: block b (c=b&7, i=b>>3) transposes+bf16-converts the B-chunk c tiles
//          (feat (512,N) f32 -> featT (N,512) bf16) -- the SAME chunk its phase B
//          reads, so featT is produced in the consuming XCD's L2. Blocks 256..412
//          also run the offs[] linear boundary scan.
// Barrier: threadfence-all -> syncthreads -> leader atomicAdd + acquire spin
//          -> threadfence -> syncthreads (device-scope release/acquire; correct
//          across non-coherent XCD L2s).
// Phase B: block b gathers 16 consecutive groups (16i..16i+15) for chunk c; wave w
//          handles 4 groups. Per 64-index window: one coalesced idx load, addresses
//          broadcast via shfl, 8 independent 128B row-slice loads in flight.
//          shfl_xor slot-reduce, 16x64 LDS tile, float4 (64B-run) stores to out.

#define NBLK 1024

__device__ __forceinline__ unsigned bf16rne(float f) {
    unsigned u = __float_as_uint(f);
    return (u + 0x7fffu + ((u >> 16) & 1u)) >> 16;
}

__global__ __launch_bounds__(256, 4) void pa_fused(
    const float* __restrict__ feat,       // (512, N)
    const int* __restrict__ idxs,         // (T,)
    const int* __restrict__ seg,          // (T,) sorted
    float* __restrict__ out,              // (512, 2048)
    unsigned short* __restrict__ featT,   // ws: (N, 512) bf16
    int* __restrict__ offs,               // ws: (G+1,)
    int* __restrict__ bar,                // ws: barrier counter (zeroed per call)
    int N, int T) {
    const int G = 2048;
    const int b   = blockIdx.x;
    const int c   = b & 7;    // B-chunk == XCD affinity heuristic
    const int i   = b >> 3;   // 0..127
    const int tid = threadIdx.x;

    __shared__ float tile[64][65];    // 16.6 KB
    __shared__ float gtile[16][64];   //  4.0 KB

    // ---------------- Phase A: transpose chunk c ----------------
    const int nTx = (N + 63) / 64;
    const int b0  = c * 64;
    const int r   = tid >> 4;   // 0..15
    const int c4  = tid & 15;   // float4 column
    for (int tx = i; tx < nTx; tx += 128) {
        const int n0 = tx * 64;
        if (n0 + 64 <= N) {
            #pragma unroll
            for (int ii = 0; ii < 4; ++ii) {
                int bb = r + 16 * ii;
                const float4 v = *(const float4*)&feat[(size_t)(b0 + bb) * N + n0 + c4 * 4];
                tile[bb][c4 * 4 + 0] = v.x;
                tile[bb][c4 * 4 + 1] = v.y;
                tile[bb][c4 * 4 + 2] = v.z;
                tile[bb][c4 * 4 + 3] = v.w;
            }
        } else {
            #pragma unroll
            for (int ii = 0; ii < 4; ++ii) {
                int bb = r + 16 * ii;
                #pragma unroll
                for (int j = 0; j < 4; ++j) {
                    int n = n0 + c4 * 4 + j;
                    tile[bb][c4 * 4 + j] = (n < N) ? feat[(size_t)(b0 + bb) * N + n] : 0.0f;
                }
            }
        }
        __syncthreads();
        uint2* outu = (uint2*)featT;  // row = 128 uint2 (512 bf16)
        #pragma unroll
        for (int ii = 0; ii < 4; ++ii) {
            int nl = r + 16 * ii;
            int n  = n0 + nl;
            if (n < N) {
                uint2 u;
                u.x = bf16rne(tile[c4 * 4 + 0][nl]) | (bf16rne(tile[c4 * 4 + 1][nl]) << 16);
                u.y = bf16rne(tile[c4 * 4 + 2][nl]) | (bf16rne(tile[c4 * 4 + 3][nl]) << 16);
                outu[(size_t)n * 128 + (b0 >> 2) + c4] = u;
            }
        }
        __syncthreads();
    }
    // offs boundary scan on blocks 256..412 (these have only 1 transpose tile)
    if (b >= 256 && b < 256 + 157) {
        int s = b - 256;
        for (int t = s * 256 + tid; t < T; t += 157 * 256) {
            int cur  = seg[t];
            int prev = (t == 0) ? -1 : seg[t - 1];
            for (int g = prev + 1; g <= cur; ++g) offs[g] = t;
            if (t == T - 1)
                for (int g = cur + 1; g <= G; ++g) offs[g] = T;
        }
    }

    // ---------------- grid barrier (device-scope) ----------------
    __threadfence();
    __syncthreads();
    if (tid == 0) {
        atomicAdd(bar, 1);
        while (__hip_atomic_load(bar, __ATOMIC_ACQUIRE, __HIP_MEMORY_SCOPE_AGENT) < NBLK) {
            __builtin_amdgcn_s_sleep(2);
        }
        __threadfence();
    }
    __syncthreads();

    // ---------------- Phase B: gather 16 groups for chunk c ----------------
    const int wave   = tid >> 6;
    const int lane   = tid & 63;
    const int lane_b = lane & 7;
    const int slot   = lane >> 3;
    const uint4* __restrict__ fp = (const uint4*)featT + c * 8 + lane_b;

#define ACC8(v)                                                        \
    do {                                                               \
        a0 += __uint_as_float((v).x << 16);                            \
        a1 += __uint_as_float((v).x & 0xffff0000u);                    \
        a2 += __uint_as_float((v).y << 16);                            \
        a3 += __uint_as_float((v).y & 0xffff0000u);                    \
        a4 += __uint_as_float((v).z << 16);                            \
        a5 += __uint_as_float((v).z & 0xffff0000u);                    \
        a6 += __uint_as_float((v).w << 16);                            \
        a7 += __uint_as_float((v).w & 0xffff0000u);                    \
    } while (0)

    for (int j = 0; j < 4; ++j) {
        const int g = i * 16 + j * 4 + wave;
        const int s = offs[g];
        const int e = offs[g + 1];
        const int cnt = e - s;

        float a0 = 0.f, a1 = 0.f, a2 = 0.f, a3 = 0.f,
              a4 = 0.f, a5 = 0.f, a6 = 0.f, a7 = 0.f;

        for (int w = s; w < e; w += 64) {
            int m = e - w;
            if (m > 64) m = 64;
            int myidx = (lane < m) ? idxs[w + lane] : 0;
            #pragma unroll
            for (int k = 0; k < 8; ++k) {
                int li = slot + 8 * k;
                int ridx = __shfl(myidx, li);
                if (li < m) {
                    uint4 v = fp[(size_t)ridx * 64];
                    ACC8(v);
                }
            }
        }

        a0 += __shfl_xor(a0, 8); a0 += __shfl_xor(a0, 16); a0 += __shfl_xor(a0, 32);
        a1 += __shfl_xor(a1, 8); a1 += __shfl_xor(a1, 16); a1 += __shfl_xor(a1, 32);
        a2 += __shfl_xor(a2, 8); a2 += __shfl_xor(a2, 16); a2 += __shfl_xor(a2, 32);
        a3 += __shfl_xor(a3, 8); a3 += __shfl_xor(a3, 16); a3 += __shfl_xor(a3, 32);
        a4 += __shfl_xor(a4, 8); a4 += __shfl_xor(a4, 16); a4 += __shfl_xor(a4, 32);
        a5 += __shfl_xor(a5, 8); a5 += __shfl_xor(a5, 16); a5 += __shfl_xor(a5, 32);
        a6 += __shfl_xor(a6, 8); a6 += __shfl_xor(a6, 16); a6 += __shfl_xor(a6, 32);
        a7 += __shfl_xor(a7, 8); a7 += __shfl_xor(a7, 16); a7 += __shfl_xor(a7, 32);

        if (slot == 0) {
            float inv = 1.0f / (float)(cnt > 0 ? cnt : 1);
            int gl = j * 4 + wave;
            int bl = lane_b * 8;
            gtile[gl][bl + 0] = a0 * inv;
            gtile[gl][bl + 1] = a1 * inv;
            gtile[gl][bl + 2] = a2 * inv;
            gtile[gl][bl + 3] = a3 * inv;
            gtile[gl][bl + 4] = a4 * inv;
            gtile[gl][bl + 5] = a5 * inv;
            gtile[gl][bl + 6] = a6 * inv;
            gtile[gl][bl + 7] = a7 * inv;
        }
    }
#undef ACC8
    __syncthreads();

    // store: thread tid -> b_local = tid>>2, 4 consecutive g (q4*4..q4*4+3)
    {
        int bb = tid >> 2;
        int q4 = tid & 3;
        float4 r4;
        r4.x = gtile[q4 * 4 + 0][bb];
        r4.y = gtile[q4 * 4 + 1][bb];
        r4.z = gtile[q4 * 4 + 2][bb];
        r4.w = gtile[q4 * 4 + 3][bb];
        *(float4*)&out[(size_t)(c * 64 + bb) * G + i * 16 + q4 * 4] = r4;
    }
}

// Fallback for unexpected shapes (correct but slow).
__global__ __launch_bounds__(256) void pa_group_mean_direct(
    const float* __restrict__ feat, const int* __restrict__ flat_indices,
    const int* __restrict__ segment_ids, float* __restrict__ out,
    int T, int B, int N, int G) {
    const int g = blockIdx.x;
    const int tid = threadIdx.x;
    __shared__ int sb[2];
    __shared__ int s_idx[256];
    if (tid < 2) {
        int target = g + tid;
        int lo = 0, hi = T;
        while (lo < hi) {
            int mid = (lo + hi) >> 1;
            if (segment_ids[mid] < target) lo = mid + 1; else hi = mid;
        }
        sb[tid] = lo;
    }
    __syncthreads();
    const int s = sb[0], e = sb[1];
    const int cnt = e - s;
    int b0 = tid * 2, b1 = tid * 2 + 1;
    float x0 = 0.f, x1 = 0.f;
    for (int base = s; base < e; base += 256) {
        int k = base + tid;
        if (k < e) s_idx[tid] = flat_indices[k];
        __syncthreads();
        int m = min(256, e - base);
        for (int jj = 0; jj < m; ++jj) {
            int idx = s_idx[jj];
            if (b0 < B) x0 += feat[(long)b0 * N + idx];
            if (b1 < B) x1 += feat[(long)b1 * N + idx];
        }
        __syncthreads();
    }
    float inv = 1.0f / (float)(cnt > 0 ? cnt : 1);
    if (b0 < B) out[(long)b0 * G + g] = x0 * inv;
    if (b1 < B) out[(long)b1 * G + g] = x1 * inv;
}

extern "C" void kernel_launch(void* const* d_in, const int* in_sizes, int n_in,
                              void* d_out, int out_size, void* d_ws, size_t ws_size,
                              hipStream_t stream) {
    const float* feat          = (const float*)d_in[0];
    const int*   flat_indices  = (const int*)d_in[1];
    const int*   segment_ids   = (const int*)d_in[2];
    float*       out           = (float*)d_out;

    const int B = 512;
    const int N = in_sizes[0] / B;      // 10000
    const int T = in_sizes[1];          // 131072
    const int G = out_size / B;         // 2048

    size_t featT_bytes = (size_t)N * B * sizeof(unsigned short);
    size_t need = featT_bytes + (size_t)(G + 1) * sizeof(int) + 16;
    if (ws_size >= need && B == 512 && G == 2048 && T >= 1) {
        unsigned short* featT = (unsigned short*)d_ws;            // (N, 512) bf16
        int* offs = (int*)((char*)d_ws + featT_bytes);            // (G+1,)
        int* bar  = offs + (G + 1);                               // barrier counter

        hipMemsetAsync(bar, 0, sizeof(int), stream);
        pa_fused<<<NBLK, 256, 0, stream>>>(feat, flat_indices, segment_ids, out,
                                           featT, offs, bar, N, T);
    } else {
        pa_group_mean_direct<<<G, 256, 0, stream>>>(feat, flat_indices, segment_ids,
                                                    out, T, B, N, G);
    }
}

// Round 6
// 26.508 us; speedup vs baseline: 9.9541x; 9.9541x over previous
//
#include <hip/hip_runtime.h>

// PoolingAggregator: out[b,g] = mean over {t : segment_ids[t]==g} of feat[b, flat_indices[t]]
// B=512, N=10000, G=2048, T=131072.
//
// Pipeline (2 kernels — R5's single-kernel grid barrier across XCDs cost 264us, reverted):
//   k1 "prep": grid (157, 9).
//       y<8 : transpose+convert feat (B,N) f32 -> featT (N,512) bf16, 64x64 tiles.
//       y==8: offs[g] = lower_bound(segment_ids, g) via linear boundary scan.
//   k2 "gather": one WAVE per (group, 64-float B-chunk); chunk = blockIdx%8 pins each
//       1.28MB featT slice to one XCD L2. Per 64-index window: one coalesced idx load
//       (software-pipelined to the next window), addresses via shfl, 8 independent
//       128B row-slice loads. Full windows skip predication. bf16 accumulate keeps
//       the hi-half's garbage low bits (error <= ~1e-3, far under threshold) to cut
//       unpack VALU 16->12 per uint4. shfl_xor slot reduce, LDS tile, float4-ish store.

__device__ __forceinline__ unsigned bf16rne(float f) {
    unsigned u = __float_as_uint(f);
    return (u + 0x7fffu + ((u >> 16) & 1u)) >> 16;
}

// grid (ceil(N/64), 9), 256 threads.
__global__ __launch_bounds__(256) void pa_prep(const float* __restrict__ feat,
                                               const int* __restrict__ seg,
                                               unsigned short* __restrict__ featT,
                                               int* __restrict__ offs,
                                               int N, int T, int G, int nXBlocks) {
    if (blockIdx.y == 8) {
        // ---- offsets: linear boundary scan over sorted seg ----
        int stride = nXBlocks * 256;
        for (int t = blockIdx.x * 256 + threadIdx.x; t < T; t += stride) {
            int cur  = seg[t];
            int prev = (t == 0) ? -1 : seg[t - 1];
            for (int g = prev + 1; g <= cur; ++g) offs[g] = t;
            if (t == T - 1) {
                for (int g = cur + 1; g <= G; ++g) offs[g] = T;
            }
        }
        return;
    }

    // ---- transpose 64(b) x 64(n) tile ----
    __shared__ float tile[64][65];
    const int n0 = blockIdx.x * 64;
    const int b0 = blockIdx.y * 64;
    const int tid = threadIdx.x;
    const int r  = tid >> 4;   // 0..15
    const int c4 = tid & 15;   // float4 column

    if (n0 + 64 <= N) {
        #pragma unroll
        for (int i = 0; i < 4; ++i) {
            int b = r + 16 * i;
            const float4 v = *(const float4*)&feat[(size_t)(b0 + b) * N + n0 + c4 * 4];
            tile[b][c4 * 4 + 0] = v.x;
            tile[b][c4 * 4 + 1] = v.y;
            tile[b][c4 * 4 + 2] = v.z;
            tile[b][c4 * 4 + 3] = v.w;
        }
    } else {
        #pragma unroll
        for (int i = 0; i < 4; ++i) {
            int b = r + 16 * i;
            #pragma unroll
            for (int j = 0; j < 4; ++j) {
                int n = n0 + c4 * 4 + j;
                tile[b][c4 * 4 + j] = (n < N) ? feat[(size_t)(b0 + b) * N + n] : 0.0f;
            }
        }
    }
    __syncthreads();

    uint2* outu = (uint2*)featT;  // row = 128 uint2 (512 bf16)
    #pragma unroll
    for (int i = 0; i < 4; ++i) {
        int nl = r + 16 * i;
        int n = n0 + nl;
        if (n >= N) continue;
        uint2 u;
        u.x = bf16rne(tile[c4 * 4 + 0][nl]) | (bf16rne(tile[c4 * 4 + 1][nl]) << 16);
        u.y = bf16rne(tile[c4 * 4 + 2][nl]) | (bf16rne(tile[c4 * 4 + 3][nl]) << 16);
        outu[(size_t)n * 128 + (b0 >> 2) + c4] = u;
    }
}

// Accumulate 8 bf16 (one uint4) into 8 f32 accs. Low halves shift up exactly;
// high halves keep the other bf16's bits as mantissa garbage (<= 1 ulp_bf16 per
// term; after the /cnt mean this is ~1e-3, far below the 1.28e-2 threshold).
#define ACC8(v)                                   \
    do {                                          \
        a0 += __uint_as_float((v).x << 16);       \
        a1 += __uint_as_float((v).x);             \
        a2 += __uint_as_float((v).y << 16);       \
        a3 += __uint_as_float((v).y);             \
        a4 += __uint_as_float((v).z << 16);       \
        a5 += __uint_as_float((v).z);             \
        a6 += __uint_as_float((v).w << 16);       \
        a7 += __uint_as_float((v).w);             \
    } while (0)

// grid = (G/4)*8 blocks, 256 threads (4 waves). Wave w of block b: group (b>>3)*4+w,
// B-chunk c = b&7 (64 floats = 8 lanes x 8 bf16), slot = lane>>3 (8 index-parallel).
__global__ __launch_bounds__(256) void pa_gather_mean_bf16(
    const unsigned short* __restrict__ featT,  // (N, 512) bf16
    const int* __restrict__ idxs,              // (T,)
    const int* __restrict__ offs,              // (G+1,)
    float* __restrict__ out,                   // (B, G)
    int G) {
    const int chunk = blockIdx.x & 7;
    const int wave  = threadIdx.x >> 6;
    const int g     = (blockIdx.x >> 3) * 4 + wave;
    const int lane  = threadIdx.x & 63;
    const int lane_b = lane & 7;
    const int slot   = lane >> 3;

    const int s = offs[g];
    const int e = offs[g + 1];
    const int cnt = e - s;

    // lane's base within a row: chunk*128B + lane_b*16B; row stride 1024B
    const char* __restrict__ fbase = (const char*)featT + chunk * 128 + lane_b * 16;

    float a0 = 0.f, a1 = 0.f, a2 = 0.f, a3 = 0.f,
          a4 = 0.f, a5 = 0.f, a6 = 0.f, a7 = 0.f;

    int w = s;
    int nrem = cnt;
    int myidx = (s + lane < e) ? idxs[s + lane] : 0;

    // full 64-index windows: no predication, next window's indices prefetched
    while (nrem >= 64) {
        int cur = myidx;
        w += 64;
        nrem -= 64;
        if (nrem > 0) myidx = (w + lane < e) ? idxs[w + lane] : 0;
        #pragma unroll
        for (int k = 0; k < 8; ++k) {
            int ridx = __shfl(cur, slot + 8 * k);
            uint4 v = *(const uint4*)(fbase + ((size_t)(unsigned)(ridx << 10)));
            ACC8(v);
        }
    }
    // tail (< 64 indices), masked
    if (nrem > 0) {
        int cur = myidx;
        #pragma unroll
        for (int k = 0; k < 8; ++k) {
            int li = slot + 8 * k;
            int ridx = __shfl(cur, li);
            if (li < nrem) {
                uint4 v = *(const uint4*)(fbase + ((size_t)(unsigned)(ridx << 10)));
                ACC8(v);
            }
        }
    }

    // reduce over the 8 slots (lane bits 3,4,5)
    a0 += __shfl_xor(a0, 8); a0 += __shfl_xor(a0, 16); a0 += __shfl_xor(a0, 32);
    a1 += __shfl_xor(a1, 8); a1 += __shfl_xor(a1, 16); a1 += __shfl_xor(a1, 32);
    a2 += __shfl_xor(a2, 8); a2 += __shfl_xor(a2, 16); a2 += __shfl_xor(a2, 32);
    a3 += __shfl_xor(a3, 8); a3 += __shfl_xor(a3, 16); a3 += __shfl_xor(a3, 32);
    a4 += __shfl_xor(a4, 8); a4 += __shfl_xor(a4, 16); a4 += __shfl_xor(a4, 32);
    a5 += __shfl_xor(a5, 8); a5 += __shfl_xor(a5, 16); a5 += __shfl_xor(a5, 32);
    a6 += __shfl_xor(a6, 8); a6 += __shfl_xor(a6, 16); a6 += __shfl_xor(a6, 32);
    a7 += __shfl_xor(a7, 8); a7 += __shfl_xor(a7, 16); a7 += __shfl_xor(a7, 32);

    __shared__ float tile[4][64];
    if (slot == 0) {
        float inv = 1.0f / (float)(cnt > 0 ? cnt : 1);
        int bl = lane_b * 8;
        tile[wave][bl + 0] = a0 * inv;
        tile[wave][bl + 1] = a1 * inv;
        tile[wave][bl + 2] = a2 * inv;
        tile[wave][bl + 3] = a3 * inv;
        tile[wave][bl + 4] = a4 * inv;
        tile[wave][bl + 5] = a5 * inv;
        tile[wave][bl + 6] = a6 * inv;
        tile[wave][bl + 7] = a7 * inv;
    }
    __syncthreads();

    // store to out (B,G): thread t -> b_local = t>>2, gi = t&3 (16B per 4 threads)
    int b_local = threadIdx.x >> 2;
    int gi      = threadIdx.x & 3;
    int gg      = (blockIdx.x >> 3) * 4 + gi;
    out[(size_t)(chunk * 64 + b_local) * G + gg] = tile[gi][b_local];
}

// Fallback for unexpected shapes (correct but slow).
__global__ __launch_bounds__(256) void pa_group_mean_direct(
    const float* __restrict__ feat, const int* __restrict__ flat_indices,
    const int* __restrict__ segment_ids, float* __restrict__ out,
    int T, int B, int N, int G) {
    const int g = blockIdx.x;
    const int tid = threadIdx.x;
    __shared__ int sb[2];
    __shared__ int s_idx[256];
    if (tid < 2) {
        int target = g + tid;
        int lo = 0, hi = T;
        while (lo < hi) {
            int mid = (lo + hi) >> 1;
            if (segment_ids[mid] < target) lo = mid + 1; else hi = mid;
        }
        sb[tid] = lo;
    }
    __syncthreads();
    const int s = sb[0], e = sb[1];
    const int cnt = e - s;
    int b0 = tid * 2, b1 = tid * 2 + 1;
    float x0 = 0.f, x1 = 0.f;
    for (int base = s; base < e; base += 256) {
        int k = base + tid;
        if (k < e) s_idx[tid] = flat_indices[k];
        __syncthreads();
        int m = min(256, e - base);
        for (int jj = 0; jj < m; ++jj) {
            int idx = s_idx[jj];
            if (b0 < B) x0 += feat[(long)b0 * N + idx];
            if (b1 < B) x1 += feat[(long)b1 * N + idx];
        }
        __syncthreads();
    }
    float inv = 1.0f / (float)(cnt > 0 ? cnt : 1);
    if (b0 < B) out[(long)b0 * G + g] = x0 * inv;
    if (b1 < B) out[(long)b1 * G + g] = x1 * inv;
}

extern "C" void kernel_launch(void* const* d_in, const int* in_sizes, int n_in,
                              void* d_out, int out_size, void* d_ws, size_t ws_size,
                              hipStream_t stream) {
    const float* feat          = (const float*)d_in[0];
    const int*   flat_indices  = (const int*)d_in[1];
    const int*   segment_ids   = (const int*)d_in[2];
    float*       out           = (float*)d_out;

    const int B = 512;
    const int N = in_sizes[0] / B;      // 10000
    const int T = in_sizes[1];          // 131072
    const int G = out_size / B;         // 2048

    size_t featT_bytes = (size_t)N * B * sizeof(unsigned short);
    size_t need = featT_bytes + (size_t)(G + 1) * sizeof(int);
    if (ws_size >= need && B == 512 && (G % 4) == 0 && T >= 1) {
        unsigned short* featT = (unsigned short*)d_ws;            // (N, 512) bf16
        int* offs = (int*)((char*)d_ws + featT_bytes);            // (G+1,)

        int nXBlocks = (N + 63) / 64;  // 157
        dim3 g1(nXBlocks, 9);
        pa_prep<<<g1, 256, 0, stream>>>(feat, segment_ids, featT, offs, N, T, G, nXBlocks);

        pa_gather_mean_bf16<<<(G / 4) * 8, 256, 0, stream>>>(featT, flat_indices, offs,
                                                             out, G);
    } else {
        pa_group_mean_direct<<<G, 256, 0, stream>>>(feat, flat_indices, segment_ids,
                                                    out, T, B, N, G);
    }
}